// Round 2
// baseline (464.531 us; speedup 1.0000x reference)
//
#include <hip/hip_runtime.h>

// SimVQuantizer: B=8, D=128 (N_CB=8 x CDIM=16), H=W=32 -> 8192 pixels.
// Outputs (FLOAT32, concatenated flat):
//   quantized  [8,128,32,32]  = 1048576   @ 0
//   indices    [8,8,32,32]    =   65536   @ 1048576
//   commitment scalar         =       1   @ 1114112
//   new_codebooks [8,1024,16] =  131072   @ 1114113
//   new_count  [8,1024]       =    8192   @ 1245185
//   new_weight [8,1024,16]    =  131072   @ 1253377

#define NCB   8
#define VOCAB 1024
#define CDIM  16
#define NPIX  8192   // B*H*W
#define HW    1024   // H*W

#define OFF_QUANT  0
#define OFF_IDX    1048576
#define OFF_COMMIT 1114112
#define OFF_NCB    1114113
#define OFF_NCNT   1245185
#define OFF_NWT    1253377

// workspace layout (floats): counts[8*1024], sums[8*1024*16], then a double
#define WS_COUNTS_OFF 0
#define WS_SUMS_OFF   (NCB * VOCAB)
#define WS_COMMIT_BYTE_OFF (size_t)((NCB * VOCAB) * 4 + (NCB * VOCAB * CDIM) * 4) // 557056
#define WS_ZERO_BYTES (WS_COMMIT_BYTE_OFF + 8)

// numpy pairwise_sum (order-preserving 8-accumulator) for n=16:
// r[j] = a[j] + a[j+8];  res = ((r0+r1)+(r2+r3)) + ((r4+r5)+(r6+r7))
__device__ __forceinline__ float npsum16(const float m[16]) {
#pragma clang fp contract(off)
  float r0 = m[0] + m[8];
  float r1 = m[1] + m[9];
  float r2 = m[2] + m[10];
  float r3 = m[3] + m[11];
  float r4 = m[4] + m[12];
  float r5 = m[5] + m[13];
  float r6 = m[6] + m[14];
  float r7 = m[7] + m[15];
  return ((r0 + r1) + (r2 + r3)) + ((r4 + r5) + (r6 + r7));
}

__device__ __forceinline__ float npsum16sq(const float a[16]) {
#pragma clang fp contract(off)
  float m[16];
#pragma unroll
  for (int d = 0; d < 16; ++d) m[d] = a[d] * a[d];
  return npsum16(m);
}

// numpy einsum (optimize=False) npyv contig order for n=16:
// l_j = (m_j + m_{j+4}) + (m_{j+8} + m_{j+12}); res = (l0+l1) + (l2+l3)
__device__ __forceinline__ float npeinsum16(const float a[16], const float b[16]) {
#pragma clang fp contract(off)
  float m[16];
#pragma unroll
  for (int d = 0; d < 16; ++d) m[d] = a[d] * b[d];
  float l0 = (m[0] + m[4]) + (m[8] + m[12]);
  float l1 = (m[1] + m[5]) + (m[9] + m[13]);
  float l2 = (m[2] + m[6]) + (m[10] + m[14]);
  float l3 = (m[3] + m[7]) + (m[11] + m[15]);
  return (l0 + l1) + (l2 + l3);
}

// v3: restore latency hiding (v2 post-mortem: kernel is latency-bound at
// 2 waves/SIMD; LDS pipe was never binding).
// 256 blocks x 1024 threads (16 waves = 4 waves/SIMD). Block: c = bx>>5,
// chunk = bx&31 (256 pixels). Each lane owns 4 pixels (zv[4][16], kept
// resident via the 128-VGPR cap from __launch_bounds__(1024,4)).
// Full 1024-entry codebook staged ONCE into 64KB LDS; wave w scans the
// contiguous ascending range [w*64, w*64+64) via wave-uniform broadcast
// ds_read_b128, software-pipelined with a next-entry register prefetch.
// All fp arithmetic / scan order / tie-break identical to v1/v2.
__global__ __launch_bounds__(1024, 4) void k_assign(
    const float* __restrict__ z, const float* __restrict__ cb,
    float* __restrict__ out, float* __restrict__ ws_counts,
    float* __restrict__ ws_sums, double* __restrict__ ws_commit) {
  __shared__ float s_cb[VOCAB * CDIM];  // 64KB: all 1024 entries
  __shared__ float s_c2[VOCAB];         // 4KB
  __shared__ float s_best[16 * 256];    // 16KB: per-wave candidate per pixel
  __shared__ int s_bi[16 * 256];        // 16KB
  __shared__ float s_red[4];

  const int c = blockIdx.x >> 5;
  const int chunk = blockIdx.x & 31;
  const int t = threadIdx.x;
  const int pix = t & 63;
  const int w = t >> 6;

  const float* cbc = cb + (size_t)c * VOCAB * CDIM;
  const float4* cb4 = reinterpret_cast<const float4*>(cbc);
  float4* s_cb4 = reinterpret_cast<float4*>(s_cb);

  // stage full codebook: 4096 float4, coalesced, 4 per thread
#pragma unroll
  for (int k = 0; k < 4; ++k) {
    const int i = k * 1024 + t;
    s_cb4[i] = cb4[i];
  }

  // ||cb||^2 for all 1024 entries (np.sum(cb*cb,-1), pairwise 8-acc order);
  // one entry per thread, from global (L2-hot, independent of s_cb staging)
  {
    float e[16];
#pragma unroll
    for (int d = 0; d < 16; ++d) e[d] = cbc[(size_t)t * CDIM + d];
    s_c2[t] = npsum16sq(e);
  }

  const int nbase = chunk * 256;    // first pixel id of this block
  const int b = nbase >> 10;        // batch (chunk of 256 stays in one b)
  const int hwb = nbase & 1023;     // base h*W + w
  const float* zbase = z + ((size_t)(b * 128 + c * 16)) * HW + hwb + pix;

  // zp[n,c,d] = z[b, c*16+d, h, w]; coalesced 64-lane loads per (r,d)
  float zv[4][16];
  float z2[4];
#pragma unroll
  for (int r = 0; r < 4; ++r) {
#pragma unroll
    for (int d = 0; d < 16; ++d) zv[r][d] = zbase[(size_t)d * HW + r * 64];
    z2[r] = npsum16sq(zv[r]);
  }

  float best[4];
  int bi[4];
#pragma unroll
  for (int r = 0; r < 4; ++r) {
    best[r] = INFINITY;
    bi[r] = 0;
  }

  __syncthreads();  // s_cb + s_c2 ready

  // wave w scans entries [w*64, w*64+64), ascending (first-wins within wave)
  const int vbase = w * 64;
  const float4* sl4 = s_cb4 + vbase * 4;  // wave-uniform address -> broadcast

  float4 q0 = sl4[0], q1 = sl4[1], q2 = sl4[2], q3 = sl4[3];
#pragma unroll 4
  for (int vo = 0; vo < 64; ++vo) {
    // prefetch next entry while computing this one
    float4 n0, n1, n2, n3;
    if (vo < 63) {
      n0 = sl4[vo * 4 + 4];
      n1 = sl4[vo * 4 + 5];
      n2 = sl4[vo * 4 + 6];
      n3 = sl4[vo * 4 + 7];
    }
    float e[16];
    e[0] = q0.x; e[1] = q0.y; e[2] = q0.z; e[3] = q0.w;
    e[4] = q1.x; e[5] = q1.y; e[6] = q1.z; e[7] = q1.w;
    e[8] = q2.x; e[9] = q2.y; e[10] = q2.z; e[11] = q2.w;
    e[12] = q3.x; e[13] = q3.y; e[14] = q3.z; e[15] = q3.w;
    const float c2v = s_c2[vbase + vo];
#pragma unroll
    for (int r = 0; r < 4; ++r) {
      const float dot = npeinsum16(zv[r], e);
      float d2;
      {
#pragma clang fp contract(off)
        d2 = (z2[r] - 2.0f * dot) + c2v;  // np: (z2-2*einsum)+c2
      }
      const bool lt = d2 < best[r];  // strict: ascending scan -> first-wins
      best[r] = lt ? d2 : best[r];
      bi[r] = lt ? (vbase + vo) : bi[r];
    }
    q0 = n0; q1 = n1; q2 = n2; q3 = n3;
  }

#pragma unroll
  for (int r = 0; r < 4; ++r) {
    s_best[w * 256 + r * 64 + pix] = best[r];
    s_bi[w * 256 + r * 64 + pix] = bi[r];
  }
  __syncthreads();

  // threads 0..255: combine the 16 per-wave candidates for pixel pl = t.
  // Wave ranges are disjoint ascending slices; break float ties by lower
  // index -> exactly np.argmin's first-wins.
  if (t < 256) {
    const int pl = t;
    float bb = s_best[pl];
    int bbi = s_bi[pl];
#pragma unroll
    for (int s = 1; s < 16; ++s) {
      const float ob = s_best[s * 256 + pl];
      const int oi = s_bi[s * 256 + pl];
      const bool take = (ob < bb) || (ob == bb && oi < bbi);
      bb = take ? ob : bb;
      bbi = take ? oi : bbi;
    }

    const int n = nbase + pl;
    const int hw = n & 1023;
    // reload this pixel's z (L1-hot, bit-identical to the zv registers)
    const float* zp = z + ((size_t)(b * 128 + c * 16)) * HW + hw;
    const float* qe = cbc + (size_t)bbi * CDIM;  // winning entry (L2-hot)
    float comm = 0.f;
#pragma unroll
    for (int d = 0; d < 16; ++d) {
      const float zval = zp[(size_t)d * HW];
      const float zq = qe[d];
      float diff, qst;
      {
#pragma clang fp contract(off)
        diff = zval - zq;
        qst = zval + (zq - zval);  // zq_st = zp + (zq - zp), as np computes
      }
      comm += diff * diff;
      out[OFF_QUANT + ((size_t)(b * 128 + c * 16 + d)) * HW + hw] = qst;
    }
    out[OFF_IDX + ((size_t)(b * NCB + c)) * HW + hw] = (float)bbi;

    atomicAdd(&ws_counts[c * VOCAB + bbi], 1.0f);
#pragma unroll
    for (int d = 0; d < 16; ++d)
      atomicAdd(&ws_sums[((size_t)(c * VOCAB + bbi)) * CDIM + d],
                zp[(size_t)d * HW]);

    // commitment: reduce across each active wave's 64 lanes
#pragma unroll
    for (int off = 32; off; off >>= 1) comm += __shfl_down(comm, off);
    if ((t & 63) == 0) s_red[t >> 6] = comm;
  }
  __syncthreads();
  if (t == 0) {
    const float cblk = (s_red[0] + s_red[1]) + (s_red[2] + s_red[3]);
    atomicAdd(ws_commit, (double)cblk);
  }
}

// EMA update + Laplace-smoothed normalization. 64 blocks x 256 threads:
// block = (c, part); every block recomputes its c's nsum (L2-cached reads),
// then writes a coalesced 1/8 slice of the outputs.
__global__ __launch_bounds__(256) void k_update(
    const float* __restrict__ ema_count, const float* __restrict__ ema_weight,
    const float* __restrict__ ws_counts, const float* __restrict__ ws_sums,
    const double* __restrict__ ws_commit, float* __restrict__ out) {
  const int c = blockIdx.x >> 3;
  const int part = blockIdx.x & 7;
  const int t = threadIdx.x;
  __shared__ float s_red[4];
  __shared__ float s_n;

  float psum = 0.f;
#pragma unroll
  for (int k = 0; k < 4; ++k) {
    const int v = k * 256 + t;
    psum += 0.99f * ema_count[c * VOCAB + v] + 0.01f * ws_counts[c * VOCAB + v];
  }
#pragma unroll
  for (int off = 32; off; off >>= 1) psum += __shfl_down(psum, off);
  if ((t & 63) == 0) s_red[t >> 6] = psum;
  __syncthreads();
  if (t == 0) s_n = (s_red[0] + s_red[1]) + (s_red[2] + s_red[3]);
  __syncthreads();
  const float nsum = s_n;
  const float veps = 0.01024f;  // VOCAB * 1e-5

  // new_count: 128 entries per block
  if (t < 128) {
    const int v = part * 128 + t;
    out[OFF_NCNT + c * VOCAB + v] =
        0.99f * ema_count[c * VOCAB + v] + 0.01f * ws_counts[c * VOCAB + v];
  }

  // new_weight / new_codebooks: 2048 elements per block, coalesced
#pragma unroll
  for (int k = 0; k < 8; ++k) {
    const int i = part * 2048 + k * 256 + t;  // element within codebook c
    const int v = i >> 4;
    const float nc =
        0.99f * ema_count[c * VOCAB + v] + 0.01f * ws_counts[c * VOCAB + v];
    const float cnt = (nc + 1e-5f) / (nsum + veps) * nsum;
    const size_t gi = (size_t)c * VOCAB * CDIM + i;
    const float nw = 0.99f * ema_weight[gi] + 0.01f * ws_sums[gi];
    out[OFF_NWT + gi] = nw;
    out[OFF_NCB + gi] = nw / cnt;
  }
  if (blockIdx.x == 0 && t == 0)
    out[OFF_COMMIT] = (float)(*ws_commit / 1048576.0);
}

extern "C" void kernel_launch(void* const* d_in, const int* in_sizes, int n_in,
                              void* d_out, int out_size, void* d_ws,
                              size_t ws_size, hipStream_t stream) {
  const float* z = (const float*)d_in[0];
  const float* codebooks = (const float*)d_in[1];
  const float* ema_count = (const float*)d_in[2];
  const float* ema_weight = (const float*)d_in[3];
  float* out = (float*)d_out;

  float* wsf = (float*)d_ws;
  float* ws_counts = wsf + WS_COUNTS_OFF;
  float* ws_sums = wsf + WS_SUMS_OFF;
  double* ws_commit = (double*)((char*)d_ws + WS_COMMIT_BYTE_OFF);

  hipMemsetAsync(d_ws, 0, WS_ZERO_BYTES, stream);

  k_assign<<<dim3(256), dim3(1024), 0, stream>>>(z, codebooks, out, ws_counts,
                                                 ws_sums, ws_commit);
  k_update<<<dim3(64), dim3(256), 0, stream>>>(ema_count, ema_weight,
                                               ws_counts, ws_sums, ws_commit,
                                               out);
}

// Round 4
// 209.087 us; speedup vs baseline: 2.2217x; 2.2217x over previous
//
#include <hip/hip_runtime.h>

// SimVQuantizer: B=8, D=128 (N_CB=8 x CDIM=16), H=W=32 -> 8192 pixels.
// Outputs (FLOAT32, concatenated flat):
//   quantized  [8,128,32,32]  = 1048576   @ 0
//   indices    [8,8,32,32]    =   65536   @ 1048576
//   commitment scalar         =       1   @ 1114112
//   new_codebooks [8,1024,16] =  131072   @ 1114113
//   new_count  [8,1024]       =    8192   @ 1245185
//   new_weight [8,1024,16]    =  131072   @ 1253377

#define NCB   8
#define VOCAB 1024
#define CDIM  16
#define NPIX  8192   // B*H*W
#define HW    1024   // H*W

#define OFF_QUANT  0
#define OFF_IDX    1048576
#define OFF_COMMIT 1114112
#define OFF_NCB    1114113
#define OFF_NCNT   1245185
#define OFF_NWT    1253377

// workspace layout (floats): counts[8*1024], sums[8*1024*16], then a double
#define WS_COUNTS_OFF 0
#define WS_SUMS_OFF   (NCB * VOCAB)
#define WS_COMMIT_BYTE_OFF (size_t)((NCB * VOCAB) * 4 + (NCB * VOCAB * CDIM) * 4) // 557056
#define WS_ZERO_BYTES (WS_COMMIT_BYTE_OFF + 8)

// numpy pairwise_sum (order-preserving 8-accumulator) for n=16:
// r[j] = a[j] + a[j+8];  res = ((r0+r1)+(r2+r3)) + ((r4+r5)+(r6+r7))
__device__ __forceinline__ float npsum16(const float m[16]) {
#pragma clang fp contract(off)
  float r0 = m[0] + m[8];
  float r1 = m[1] + m[9];
  float r2 = m[2] + m[10];
  float r3 = m[3] + m[11];
  float r4 = m[4] + m[12];
  float r5 = m[5] + m[13];
  float r6 = m[6] + m[14];
  float r7 = m[7] + m[15];
  return ((r0 + r1) + (r2 + r3)) + ((r4 + r5) + (r6 + r7));
}

__device__ __forceinline__ float npsum16sq(const float a[16]) {
#pragma clang fp contract(off)
  float m[16];
#pragma unroll
  for (int d = 0; d < 16; ++d) m[d] = a[d] * a[d];
  return npsum16(m);
}

// One entry's distance + argmin step. numpy einsum (optimize=False) npyv
// contig order for n=16, then (z2 - 2*dot) + c2 — bit-identical to v1.
__device__ __forceinline__ void proc_entry(const float zv[16],
                                           const float e[16], float c2v,
                                           float z2, int idx, float& best,
                                           int& bi) {
#pragma clang fp contract(off)
  float m[16];
#pragma unroll
  for (int d = 0; d < 16; ++d) m[d] = zv[d] * e[d];
  float l0 = (m[0] + m[4]) + (m[8] + m[12]);
  float l1 = (m[1] + m[5]) + (m[9] + m[13]);
  float l2 = (m[2] + m[6]) + (m[10] + m[14]);
  float l3 = (m[3] + m[7]) + (m[11] + m[15]);
  const float dot = (l0 + l1) + (l2 + l3);
  const float d2 = (z2 - 2.0f * dot) + c2v;
  const bool lt = d2 < best;  // strict: ascending scan -> first-wins
  best = lt ? d2 : best;
  bi = lt ? idx : bi;
}

// v5: v1 shell (1024 blocks x 512 threads, R=1), but the codebook entries
// stream from GLOBAL memory at wave-uniform addresses in plain C — the
// compiler selects s_load_dwordx16 (or a uniform coalesced VMEM load) with
// correct waitcnt/regalloc handling. v4's hand-rolled inline-asm version
// of the same idea corrupted data (async SGPR writes vs regalloc copies).
// This removes the inner loop's 4x ds_read_b128 (v1's binding resource:
// ~92us aggregate LDS-pipe time vs ~31us VALU). Only c2 stays in LDS
// (1 uniform ds_read_b32/entry ~= 10us aggregate).
// Wave w scans contiguous ascending [w*128, w*128+128); cross-wave combine
// tie-breaks on lower index -> exactly np.argmin first-wins.
// LDS ~8KB, target VGPR <= 64 -> up to 8 waves/SIMD to hide SMEM latency.
__global__ __launch_bounds__(512, 4) void k_assign(
    const float* __restrict__ z, const float* __restrict__ cb,
    float* __restrict__ out, float* __restrict__ ws_counts,
    float* __restrict__ ws_sums, double* __restrict__ ws_commit) {
  __shared__ float s_c2[VOCAB];    // 4KB
  __shared__ float s_best[8 * 64]; // 2KB
  __shared__ int s_bi[8 * 64];     // 2KB

  const int c = blockIdx.x >> 7;
  const int pchunk = blockIdx.x & 127;
  const int t = threadIdx.x;
  const int pix = t & 63;
  const int w = t >> 6;
  // provably wave-uniform wave id -> scalar (SGPR) entry addressing below
  const int wu = __builtin_amdgcn_readfirstlane(w);

  const float* cbc = cb + (size_t)c * VOCAB * CDIM;

  // ||cb||^2 for all 1024 entries (np.sum(cb*cb,-1), pairwise 8-acc order)
  for (int v = t; v < VOCAB; v += 512) {
    float e[16];
#pragma unroll
    for (int d = 0; d < 16; ++d) e[d] = cbc[(size_t)v * CDIM + d];
    s_c2[v] = npsum16sq(e);
  }

  const int n = pchunk * 64 + pix;  // pixel id in [0, 8192)
  const int b = n >> 10;            // batch
  const int hw = n & 1023;          // h*W + w

  // zp[n,c,d] = z[b, c*16+d, h, w]; 64-lane coalesced per d
  const float* zbase = z + ((size_t)(b * 128 + c * 16)) * HW + hw;
  float zv[16];
#pragma unroll
  for (int d = 0; d < 16; ++d) zv[d] = zbase[(size_t)d * HW];

  const float z2 = npsum16sq(zv);

  __syncthreads();  // s_c2 ready

  // wave wu scans entries [wu*128, wu*128+128), ascending
  const int vbase = wu * 128;
  const float* ep = cbc + (size_t)vbase * CDIM;  // uniform (SGPR) pointer

  float best = INFINITY;
  int bi = 0;

#pragma unroll 2
  for (int k = 0; k < 128; k += 2) {
    // two entries per body; unroll 2 -> 4 entries of load-ahead slack for
    // the scheduler. All addresses uniform -> scalar loads.
    float ea[16], eb[16];
#pragma unroll
    for (int d = 0; d < 16; ++d) ea[d] = ep[(size_t)k * CDIM + d];
#pragma unroll
    for (int d = 0; d < 16; ++d) eb[d] = ep[(size_t)(k + 1) * CDIM + d];
    const float cv0 = s_c2[vbase + k];
    const float cv1 = s_c2[vbase + k + 1];
    proc_entry(zv, ea, cv0, z2, vbase + k, best, bi);
    proc_entry(zv, eb, cv1, z2, vbase + k + 1, best, bi);
  }

  s_best[w * 64 + pix] = best;
  s_bi[w * 64 + pix] = bi;
  __syncthreads();

  // wave 0: combine the 8 per-wave candidates. Wave slices are disjoint
  // ascending ranges; break float ties by lower index -> np.argmin
  // first-wins exactly.
  if (t < 64) {
    best = s_best[t];
    bi = s_bi[t];
#pragma unroll
    for (int s = 1; s < 8; ++s) {
      const float ob = s_best[s * 64 + t];
      const int oi = s_bi[s * 64 + t];
      const bool take = (ob < best) || (ob == best && oi < bi);
      best = take ? ob : best;
      bi = take ? oi : bi;
    }

    // t<64 => wave 0, pix == t: zv holds THIS pixel's z (bit-identical)
    const float* qe = cbc + (size_t)bi * CDIM;  // winning entry (L2-hot)
    float comm = 0.f;
#pragma unroll
    for (int d = 0; d < 16; ++d) {
      float zq = qe[d];
      float diff, qst;
      {
#pragma clang fp contract(off)
        diff = zv[d] - zq;
        qst = zv[d] + (zq - zv[d]);  // zq_st = zp + (zq - zp), as np computes
      }
      comm += diff * diff;
      out[OFF_QUANT + ((size_t)(b * 128 + c * 16 + d)) * HW + hw] = qst;
    }
    out[OFF_IDX + ((size_t)(b * NCB + c)) * HW + hw] = (float)bi;

    atomicAdd(&ws_counts[c * VOCAB + bi], 1.0f);
#pragma unroll
    for (int d = 0; d < 16; ++d)
      atomicAdd(&ws_sums[((size_t)(c * VOCAB + bi)) * CDIM + d], zv[d]);

    // commitment: reduce across wave 0's 64 lanes, one f64 atomic per block
#pragma unroll
    for (int off = 32; off; off >>= 1) comm += __shfl_down(comm, off);
    if (t == 0) atomicAdd(ws_commit, (double)comm);
  }
}

// EMA update + Laplace-smoothed normalization. 64 blocks x 256 threads:
// block = (c, part); every block recomputes its c's nsum (L2-cached reads),
// then writes a coalesced 1/8 slice of the outputs.
__global__ __launch_bounds__(256) void k_update(
    const float* __restrict__ ema_count, const float* __restrict__ ema_weight,
    const float* __restrict__ ws_counts, const float* __restrict__ ws_sums,
    const double* __restrict__ ws_commit, float* __restrict__ out) {
  const int c = blockIdx.x >> 3;
  const int part = blockIdx.x & 7;
  const int t = threadIdx.x;
  __shared__ float s_red[4];
  __shared__ float s_n;

  float psum = 0.f;
#pragma unroll
  for (int k = 0; k < 4; ++k) {
    const int v = k * 256 + t;
    psum += 0.99f * ema_count[c * VOCAB + v] + 0.01f * ws_counts[c * VOCAB + v];
  }
#pragma unroll
  for (int off = 32; off; off >>= 1) psum += __shfl_down(psum, off);
  if ((t & 63) == 0) s_red[t >> 6] = psum;
  __syncthreads();
  if (t == 0) s_n = (s_red[0] + s_red[1]) + (s_red[2] + s_red[3]);
  __syncthreads();
  const float nsum = s_n;
  const float veps = 0.01024f;  // VOCAB * 1e-5

  // new_count: 128 entries per block
  if (t < 128) {
    const int v = part * 128 + t;
    out[OFF_NCNT + c * VOCAB + v] =
        0.99f * ema_count[c * VOCAB + v] + 0.01f * ws_counts[c * VOCAB + v];
  }

  // new_weight / new_codebooks: 2048 elements per block, coalesced
#pragma unroll
  for (int k = 0; k < 8; ++k) {
    const int i = part * 2048 + k * 256 + t;  // element within codebook c
    const int v = i >> 4;
    const float nc =
        0.99f * ema_count[c * VOCAB + v] + 0.01f * ws_counts[c * VOCAB + v];
    const float cnt = (nc + 1e-5f) / (nsum + veps) * nsum;
    const size_t gi = (size_t)c * VOCAB * CDIM + i;
    const float nw = 0.99f * ema_weight[gi] + 0.01f * ws_sums[gi];
    out[OFF_NWT + gi] = nw;
    out[OFF_NCB + gi] = nw / cnt;
  }
  if (blockIdx.x == 0 && t == 0)
    out[OFF_COMMIT] = (float)(*ws_commit / 1048576.0);
}

extern "C" void kernel_launch(void* const* d_in, const int* in_sizes, int n_in,
                              void* d_out, int out_size, void* d_ws,
                              size_t ws_size, hipStream_t stream) {
  const float* z = (const float*)d_in[0];
  const float* codebooks = (const float*)d_in[1];
  const float* ema_count = (const float*)d_in[2];
  const float* ema_weight = (const float*)d_in[3];
  float* out = (float*)d_out;

  float* wsf = (float*)d_ws;
  float* ws_counts = wsf + WS_COUNTS_OFF;
  float* ws_sums = wsf + WS_SUMS_OFF;
  double* ws_commit = (double*)((char*)d_ws + WS_COMMIT_BYTE_OFF);

  hipMemsetAsync(d_ws, 0, WS_ZERO_BYTES, stream);

  k_assign<<<dim3(1024), dim3(512), 0, stream>>>(z, codebooks, out, ws_counts,
                                                 ws_sums, ws_commit);
  k_update<<<dim3(64), dim3(256), 0, stream>>>(ema_count, ema_weight,
                                               ws_counts, ws_sums, ws_commit,
                                               out);
}

// Round 5
// 143.790 us; speedup vs baseline: 3.2306x; 1.4541x over previous
//
#include <hip/hip_runtime.h>

// SimVQuantizer: B=8, D=128 (N_CB=8 x CDIM=16), H=W=32 -> 8192 pixels.
// Outputs (FLOAT32, concatenated flat):
//   quantized  [8,128,32,32]  = 1048576   @ 0
//   indices    [8,8,32,32]    =   65536   @ 1048576
//   commitment scalar         =       1   @ 1114112
//   new_codebooks [8,1024,16] =  131072   @ 1114113
//   new_count  [8,1024]       =    8192   @ 1245185
//   new_weight [8,1024,16]    =  131072   @ 1253377

#define NCB   8
#define VOCAB 1024
#define CDIM  16
#define NPIX  8192   // B*H*W
#define HW    1024   // H*W

#define OFF_QUANT  0
#define OFF_IDX    1048576
#define OFF_COMMIT 1114112
#define OFF_NCB    1114113
#define OFF_NCNT   1245185
#define OFF_NWT    1253377

// workspace layout (floats):
//   counts    [8*1024]          @ 0         (written dense by k_stats)
//   sums_T    [8][16][1024]     @ 8192      (transposed [c][d][v], dense)
//   commit_arr[1024]            @ 139264    (per-block partials, dense)
// No memset needed: every word is written before it is read.
#define WS_COUNTS_OFF 0
#define WS_SUMS_OFF   (NCB * VOCAB)
#define WS_CARR_OFF   (NCB * VOCAB + NCB * VOCAB * CDIM)

// numpy pairwise_sum (order-preserving 8-accumulator) for n=16:
// r[j] = a[j] + a[j+8];  res = ((r0+r1)+(r2+r3)) + ((r4+r5)+(r6+r7))
__device__ __forceinline__ float npsum16(const float m[16]) {
#pragma clang fp contract(off)
  float r0 = m[0] + m[8];
  float r1 = m[1] + m[9];
  float r2 = m[2] + m[10];
  float r3 = m[3] + m[11];
  float r4 = m[4] + m[12];
  float r5 = m[5] + m[13];
  float r6 = m[6] + m[14];
  float r7 = m[7] + m[15];
  return ((r0 + r1) + (r2 + r3)) + ((r4 + r5) + (r6 + r7));
}

__device__ __forceinline__ float npsum16sq(const float a[16]) {
#pragma clang fp contract(off)
  float m[16];
#pragma unroll
  for (int d = 0; d < 16; ++d) m[d] = a[d] * a[d];
  return npsum16(m);
}

// One entry's distance + argmin step. numpy einsum (optimize=False) npyv
// contig order for n=16, then (z2 - 2*dot) + c2 — bit-identical to v1.
__device__ __forceinline__ void proc_entry(const float zv[16],
                                           const float e[16], float c2v,
                                           float z2, int idx, float& best,
                                           int& bi) {
#pragma clang fp contract(off)
  float m[16];
#pragma unroll
  for (int d = 0; d < 16; ++d) m[d] = zv[d] * e[d];
  float l0 = (m[0] + m[4]) + (m[8] + m[12]);
  float l1 = (m[1] + m[5]) + (m[9] + m[13]);
  float l2 = (m[2] + m[6]) + (m[10] + m[14]);
  float l3 = (m[3] + m[7]) + (m[11] + m[15]);
  const float dot = (l0 + l1) + (l2 + l3);
  const float d2 = (z2 - 2.0f * dot) + c2v;
  const bool lt = d2 < best;  // strict: ascending scan -> first-wins
  best = lt ? d2 : best;
  bi = lt ? idx : bi;
}

// v6: v5's scalar-stream inner loop, but the global-atomic stats path is
// GONE. Post-mortem of v1/v2/v5: all landed at ~150us with WRITE_SIZE
// identical to the byte (38.9MB vs ~4.5MB logical) — the 1.1M device-scope
// atomicAdds (65536 winners x 17) were a structure-independent TCC-RMW
// floor. k_assign now writes only quantized/idx + a per-block commitment
// partial (plain store). Binning moved to k_stats (LDS-atomic, dense out).
__global__ __launch_bounds__(512, 4) void k_assign(
    const float* __restrict__ z, const float* __restrict__ cb,
    float* __restrict__ out, float* __restrict__ ws_commit_arr) {
  __shared__ float s_c2[VOCAB];    // 4KB
  __shared__ float s_best[8 * 64]; // 2KB
  __shared__ int s_bi[8 * 64];     // 2KB

  const int c = blockIdx.x >> 7;
  const int pchunk = blockIdx.x & 127;
  const int t = threadIdx.x;
  const int pix = t & 63;
  const int w = t >> 6;
  // provably wave-uniform wave id -> scalar (SGPR) entry addressing below
  const int wu = __builtin_amdgcn_readfirstlane(w);

  const float* cbc = cb + (size_t)c * VOCAB * CDIM;

  // ||cb||^2 for all 1024 entries (np.sum(cb*cb,-1), pairwise 8-acc order)
  for (int v = t; v < VOCAB; v += 512) {
    float e[16];
#pragma unroll
    for (int d = 0; d < 16; ++d) e[d] = cbc[(size_t)v * CDIM + d];
    s_c2[v] = npsum16sq(e);
  }

  const int n = pchunk * 64 + pix;  // pixel id in [0, 8192)
  const int b = n >> 10;            // batch
  const int hw = n & 1023;          // h*W + w

  // zp[n,c,d] = z[b, c*16+d, h, w]; 64-lane coalesced per d
  const float* zbase = z + ((size_t)(b * 128 + c * 16)) * HW + hw;
  float zv[16];
#pragma unroll
  for (int d = 0; d < 16; ++d) zv[d] = zbase[(size_t)d * HW];

  const float z2 = npsum16sq(zv);

  __syncthreads();  // s_c2 ready

  // wave wu scans entries [wu*128, wu*128+128), ascending
  const int vbase = wu * 128;
  const float* ep = cbc + (size_t)vbase * CDIM;  // uniform (SGPR) pointer

  float best = INFINITY;
  int bi = 0;

#pragma unroll 2
  for (int k = 0; k < 128; k += 2) {
    // two entries per body; unroll 2 -> 4 entries of load-ahead slack for
    // the scheduler. All addresses uniform -> scalar loads.
    float ea[16], eb[16];
#pragma unroll
    for (int d = 0; d < 16; ++d) ea[d] = ep[(size_t)k * CDIM + d];
#pragma unroll
    for (int d = 0; d < 16; ++d) eb[d] = ep[(size_t)(k + 1) * CDIM + d];
    const float cv0 = s_c2[vbase + k];
    const float cv1 = s_c2[vbase + k + 1];
    proc_entry(zv, ea, cv0, z2, vbase + k, best, bi);
    proc_entry(zv, eb, cv1, z2, vbase + k + 1, best, bi);
  }

  s_best[w * 64 + pix] = best;
  s_bi[w * 64 + pix] = bi;
  __syncthreads();

  // wave 0: combine the 8 per-wave candidates. Wave slices are disjoint
  // ascending ranges; break float ties by lower index -> np.argmin
  // first-wins exactly.
  if (t < 64) {
    best = s_best[t];
    bi = s_bi[t];
#pragma unroll
    for (int s = 1; s < 8; ++s) {
      const float ob = s_best[s * 64 + t];
      const int oi = s_bi[s * 64 + t];
      const bool take = (ob < best) || (ob == best && oi < bi);
      best = take ? ob : best;
      bi = take ? oi : bi;
    }

    // t<64 => wave 0, pix == t: zv holds THIS pixel's z (bit-identical)
    const float* qe = cbc + (size_t)bi * CDIM;  // winning entry (L2-hot)
    float comm = 0.f;
#pragma unroll
    for (int d = 0; d < 16; ++d) {
      float zq = qe[d];
      float diff, qst;
      {
#pragma clang fp contract(off)
        diff = zv[d] - zq;
        qst = zv[d] + (zq - zv[d]);  // zq_st = zp + (zq - zp), as np computes
      }
      comm += diff * diff;
      out[OFF_QUANT + ((size_t)(b * 128 + c * 16 + d)) * HW + hw] = qst;
    }
    out[OFF_IDX + ((size_t)(b * NCB + c)) * HW + hw] = (float)bi;

    // commitment partial: reduce across wave 0's 64 lanes, ONE plain store
    // per block (no atomics anywhere in this kernel).
#pragma unroll
    for (int off = 32; off; off >>= 1) comm += __shfl_down(comm, off);
    if (t == 0) ws_commit_arr[blockIdx.x] = comm;
  }
}

// k_stats: bin winners into counts/sums with LDS atomics; dense global
// writes, ZERO global atomics. Grid: 128 blocks = (c, d); block (c,d)
// exclusively owns sums_T[c][d][*]; d==0 blocks also own counts[c][*].
// Reads idx from `out` (same-stream ordering makes k_assign's writes
// visible) and one z-plane per block, both fully coalesced.
__global__ __launch_bounds__(1024) void k_stats(
    const float* __restrict__ z, const float* __restrict__ outbuf,
    float* __restrict__ ws_counts, float* __restrict__ ws_sums_t) {
  __shared__ float s_sum[VOCAB];  // 4KB
  __shared__ float s_cnt[VOCAB];  // 4KB (used only by d==0 blocks)
  const int c = blockIdx.x >> 4;
  const int d = blockIdx.x & 15;
  const int t = threadIdx.x;

  s_sum[t] = 0.f;
  if (d == 0) s_cnt[t] = 0.f;
  __syncthreads();

#pragma unroll
  for (int k = 0; k < 8; ++k) {  // k = batch b; pixel n = k*1024 + t
    const int bi = (int)outbuf[OFF_IDX + ((size_t)(k * NCB + c)) * HW + t];
    const float zval = z[((size_t)(k * 128 + c * 16 + d)) * HW + t];
    atomicAdd(&s_sum[bi], zval);       // ds_add_f32: banked, cheap
    if (d == 0) atomicAdd(&s_cnt[bi], 1.0f);
  }
  __syncthreads();

  ws_sums_t[((size_t)(c * CDIM + d)) * VOCAB + t] = s_sum[t];  // coalesced
  if (d == 0) ws_counts[c * VOCAB + t] = s_cnt[t];
}

// EMA update + Laplace-smoothed normalization. 64 blocks x 256 threads:
// block = (c, part); every block recomputes its c's nsum (L2-cached reads),
// then writes a coalesced 1/8 slice of the outputs. Block 0 additionally
// reduces the 1024 commitment partials (f64) and writes the scalar.
__global__ __launch_bounds__(256) void k_update(
    const float* __restrict__ ema_count, const float* __restrict__ ema_weight,
    const float* __restrict__ ws_counts, const float* __restrict__ ws_sums_t,
    const float* __restrict__ ws_commit_arr, float* __restrict__ out) {
  const int c = blockIdx.x >> 3;
  const int part = blockIdx.x & 7;
  const int t = threadIdx.x;
  __shared__ float s_red[4];
  __shared__ float s_n;
  __shared__ double s_dred[4];

  float psum = 0.f;
#pragma unroll
  for (int k = 0; k < 4; ++k) {
    const int v = k * 256 + t;
    psum += 0.99f * ema_count[c * VOCAB + v] + 0.01f * ws_counts[c * VOCAB + v];
  }
#pragma unroll
  for (int off = 32; off; off >>= 1) psum += __shfl_down(psum, off);
  if ((t & 63) == 0) s_red[t >> 6] = psum;
  __syncthreads();
  if (t == 0) s_n = (s_red[0] + s_red[1]) + (s_red[2] + s_red[3]);
  __syncthreads();
  const float nsum = s_n;
  const float veps = 0.01024f;  // VOCAB * 1e-5

  // new_count: 128 entries per block
  if (t < 128) {
    const int v = part * 128 + t;
    out[OFF_NCNT + c * VOCAB + v] =
        0.99f * ema_count[c * VOCAB + v] + 0.01f * ws_counts[c * VOCAB + v];
  }

  // new_weight / new_codebooks: 2048 elements per block, coalesced stores;
  // sums read from the transposed [c][d][v] layout (L1/L2-hot, 0.5MB total)
#pragma unroll
  for (int k = 0; k < 8; ++k) {
    const int i = part * 2048 + k * 256 + t;  // element within codebook c
    const int v = i >> 4;
    const int d = i & 15;
    const float nc =
        0.99f * ema_count[c * VOCAB + v] + 0.01f * ws_counts[c * VOCAB + v];
    const float cnt = (nc + 1e-5f) / (nsum + veps) * nsum;
    const size_t gi = (size_t)c * VOCAB * CDIM + i;
    const float nw = 0.99f * ema_weight[gi] +
                     0.01f * ws_sums_t[((size_t)(c * CDIM + d)) * VOCAB + v];
    out[OFF_NWT + gi] = nw;
    out[OFF_NCB + gi] = nw / cnt;
  }

  if (blockIdx.x == 0) {
    double ps = 0.0;
#pragma unroll
    for (int k = 0; k < 4; ++k) ps += (double)ws_commit_arr[k * 256 + t];
#pragma unroll
    for (int off = 32; off; off >>= 1) ps += __shfl_down(ps, off);
    if ((t & 63) == 0) s_dred[t >> 6] = ps;
    __syncthreads();
    if (t == 0)
      out[OFF_COMMIT] =
          (float)(((s_dred[0] + s_dred[1]) + (s_dred[2] + s_dred[3])) /
                  1048576.0);
  }
}

extern "C" void kernel_launch(void* const* d_in, const int* in_sizes, int n_in,
                              void* d_out, int out_size, void* d_ws,
                              size_t ws_size, hipStream_t stream) {
  const float* z = (const float*)d_in[0];
  const float* codebooks = (const float*)d_in[1];
  const float* ema_count = (const float*)d_in[2];
  const float* ema_weight = (const float*)d_in[3];
  float* out = (float*)d_out;

  float* wsf = (float*)d_ws;
  float* ws_counts = wsf + WS_COUNTS_OFF;
  float* ws_sums_t = wsf + WS_SUMS_OFF;
  float* ws_commit_arr = wsf + WS_CARR_OFF;

  // no memset: every workspace word is written densely before it is read

  k_assign<<<dim3(1024), dim3(512), 0, stream>>>(z, codebooks, out,
                                                 ws_commit_arr);
  k_stats<<<dim3(128), dim3(1024), 0, stream>>>(z, out, ws_counts, ws_sums_t);
  k_update<<<dim3(64), dim3(256), 0, stream>>>(ema_count, ema_weight,
                                               ws_counts, ws_sums_t,
                                               ws_commit_arr, out);
}